// Round 1
// baseline (141.243 us; speedup 1.0000x reference)
//
#include <hip/hip_runtime.h>

#define NL 133
#define HT 60
#define WD 108
#define PIX (HT*WD)          // 6480
#define CT 432               // 3*12*12 channels after unfold
#define L45 45               // patches
#define STR 440              // LDS row stride in halves (880B: 16B-aligned rows)
#define BTC 4
#define NB (BTC*NL)          // 532 blocks
#define EPIX (3*PIX)         // 19440 elements per (bt) image

typedef _Float16 f16;
typedef _Float16 h2 __attribute__((ext_vector_type(2)));
typedef _Float16 h4 __attribute__((ext_vector_type(4)));

__device__ __forceinline__ h2 lo2(h4 v){ return __builtin_shufflevector(v, v, 0, 1); }
__device__ __forceinline__ h2 hi2(h4 v){ return __builtin_shufflevector(v, v, 2, 3); }

__device__ __forceinline__ float fdot2f(h2 a, h2 b, float c){
#if __has_builtin(__builtin_amdgcn_fdot2)
  return __builtin_amdgcn_fdot2(a, b, c, false);
#else
  return c + (float)a[0]*(float)b[0] + (float)a[1]*(float)b[1];
#endif
}

// ---- S transpose: (bt, pix, n) f32 -> (bt*133+n, pix) f16 ----
__global__ __launch_bounds__(256) void ktrans(const float* __restrict__ S,
                                              f16* __restrict__ St){
  __shared__ float tile[64][135];           // pad 135: stride-135 reads hit 32 banks
  int blk = blockIdx.x;
  int bt = blk / 102, t = blk % 102;
  int pix0 = t * 64;
  int tid = threadIdx.x;
  for (int r = tid; r < 64*NL; r += 256){
    int p = r / NL, nn = r % NL;
    int pix = pix0 + p;
    if (pix < PIX) tile[p][nn] = S[((size_t)bt*PIX + pix)*NL + nn];  // coalesced along n
  }
  __syncthreads();
  for (int w = tid; w < 64*NL; w += 256){
    int nn = w / 64, p = w % 64;
    int pix = pix0 + p;
    if (pix < PIX) St[((size_t)(bt*NL + nn))*PIX + pix] = (f16)tile[p][nn]; // coalesced u16
  }
}

// ---- main: per (bt,n): build U,Kt in LDS; Wm = U^T Kt; L1-normalize rows;
//      out(c,i) = sum_j Wm[i][j]*Kt[c][j]; store per-layer (scr) or atomic ----
template<bool USE_SCR, bool USE_ST>
__global__ __launch_bounds__(256) void kmain(const float* __restrict__ I,
                                             const float* __restrict__ S,
                                             const float* __restrict__ M,
                                             const f16* __restrict__ St,
                                             f16* __restrict__ scr,
                                             float* __restrict__ outAcc){
  __shared__ f16 bufU[L45*STR];   // U [p][c]; later reused as Wm2 (h2 duplicated)
  __shared__ f16 bufK[L45*STR];   // Kt [p][c]
  int b  = blockIdx.x;
  int bt = b / NL, n = b % NL;
  int tid = threadIdx.x;
  const float* Ib = I + (size_t)bt*EPIX;
  const float* Mb = M + (size_t)bt*PIX;

  // Phase A: build U/Kt tiles. thread <-> channel c; loop over 45 patches.
  for (int c = tid; c < CT; c += 256){
    int ch = c / 144, kr = c % 144;
    int ky = kr / 12, kx = kr % 12;
    const float* Ich = Ib + ch*PIX;
    int p = 0;
    #pragma unroll
    for (int py = 0; py < 5; ++py){
      int row = (py*12 + ky)*WD;
      #pragma unroll
      for (int px = 0; px < 9; ++px, ++p){
        int x = px*12 + kx;
        float sv;
        if (USE_ST) sv = (float)St[(size_t)b*PIX + row + x];
        else        sv = S[((size_t)bt*PIX + row + x)*NL + n];
        float iv = Ich[row + x];
        float mv = Mb[row + x];
        float v = iv * sv;
        float u = v * mv;
        bufU[p*STR + c] = (f16)u;
        bufK[p*STR + c] = (f16)(v - u);
      }
    }
  }
  __syncthreads();

  // Phase B: Wm[p][q] = sum_c U[p][c]*Kt[q][c]; 16x16 threads (15x15 active), 3x3 tile.
  int tx = tid & 15, ty = tid >> 4;
  float acc[3][3] = {{0.f,0.f,0.f},{0.f,0.f,0.f},{0.f,0.f,0.f}};
  if (tx < 15 && ty < 15){
    const f16* up = &bufU[(ty*3)*STR];
    const f16* kp = &bufK[(tx*3)*STR];
    for (int cc = 0; cc < CT; cc += 4){
      h4 u0 = *(const h4*)&up[cc];
      h4 u1 = *(const h4*)&up[STR + cc];
      h4 u2 = *(const h4*)&up[2*STR + cc];
      h4 k0 = *(const h4*)&kp[cc];
      h4 k1 = *(const h4*)&kp[STR + cc];
      h4 k2 = *(const h4*)&kp[2*STR + cc];
      h4 uu[3] = {u0,u1,u2}; h4 kk[3] = {k0,k1,k2};
      #pragma unroll
      for (int i = 0; i < 3; ++i)
        #pragma unroll
        for (int j = 0; j < 3; ++j){
          acc[i][j] = fdot2f(lo2(uu[i]), lo2(kk[j]), acc[i][j]);
          acc[i][j] = fdot2f(hi2(uu[i]), hi2(kk[j]), acc[i][j]);
        }
    }
  }
  // row L1 over q: reduce across the 16 tx lanes (tx==15 lanes hold zeros)
  float inv3[3];
  #pragma unroll
  for (int i = 0; i < 3; ++i){
    float rs = fabsf(acc[i][0]) + fabsf(acc[i][1]) + fabsf(acc[i][2]);
    rs += __shfl_xor(rs, 1); rs += __shfl_xor(rs, 2);
    rs += __shfl_xor(rs, 4); rs += __shfl_xor(rs, 8);
    inv3[i] = 1.0f / fmaxf(rs, 1e-12f);
  }
  __syncthreads();   // all stage-1 LDS reads done before overwriting bufU

  // Phase D: write normalized Wm duplicated into h2 pairs over dead U buffer.
  h2* Wm2 = (h2*)bufU;   // [i][j], row stride 48 h2
  if (tx < 15 && ty < 15){
    #pragma unroll
    for (int i = 0; i < 3; ++i)
      #pragma unroll
      for (int j = 0; j < 3; ++j){
        f16 w = (f16)(acc[i][j] * inv3[i]);
        h2 wp; wp[0] = w; wp[1] = w;
        Wm2[(ty*3 + i)*48 + (tx*3 + j)] = wp;
      }
  }
  __syncthreads();

  // Phase E: out(c0..c0+7, i0..i0+4) = sum_j Wm[i][j] * KtRow_j[c-vec]
  for (int slot = tid; slot < 486; slot += 256){
    int ii = slot / 54, cg = slot % 54;
    int i0 = ii*5, c0 = cg*8;
    h2 a[5][4];
    #pragma unroll
    for (int t = 0; t < 5; ++t)
      #pragma unroll
      for (int u = 0; u < 4; ++u){ a[t][u][0] = (f16)0.f; a[t][u][1] = (f16)0.f; }
    for (int j = 0; j < L45; ++j){
      h4 ka = *(const h4*)&bufK[j*STR + c0];
      h4 kb = *(const h4*)&bufK[j*STR + c0 + 4];
      h2 kp0 = lo2(ka), kp1 = hi2(ka), kp2 = lo2(kb), kp3 = hi2(kb);
      #pragma unroll
      for (int t = 0; t < 5; ++t){
        h2 w = Wm2[(i0 + t)*48 + j];     // uniform across lanes -> LDS broadcast
        a[t][0] = w*kp0 + a[t][0];
        a[t][1] = w*kp1 + a[t][1];
        a[t][2] = w*kp2 + a[t][2];
        a[t][3] = w*kp3 + a[t][3];
      }
    }
    #pragma unroll
    for (int t = 0; t < 5; ++t){
      int i = i0 + t;
      int iy = i / 9, ix = i % 9;
      int rowb = iy*12*WD + ix*12;
      #pragma unroll
      for (int u = 0; u < 4; ++u){
        int c = c0 + 2*u;                 // even -> kx even -> pixel pair contiguous
        int ch = c / 144, kr = c % 144;
        int ky = kr / 12, kx = kr % 12;
        int pix = ch*PIX + rowb + ky*WD + kx;
        if (USE_SCR){
          *(h2*)&scr[(size_t)b*EPIX + pix] = a[t][u];
        } else {
          atomicAdd(&outAcc[(size_t)bt*EPIX + pix],     (float)a[t][u][0]);
          atomicAdd(&outAcc[(size_t)bt*EPIX + pix + 1], (float)a[t][u][1]);
        }
      }
    }
  }
}

// ---- reduce over layers + final blend ----
__global__ __launch_bounds__(256) void kreduce(const float* __restrict__ I,
                                               const float* __restrict__ M,
                                               const f16* __restrict__ scr,
                                               float* __restrict__ out){
  int g = blockIdx.x*256 + threadIdx.x;
  if (g >= BTC*EPIX) return;
  int bt = g / EPIX, e = g % EPIX;
  const f16* p = scr + (size_t)bt*NL*EPIX + e;
  float a = 0.f;
  for (int nn = 0; nn < NL; ++nn) a += (float)p[(size_t)nn*EPIX];
  float m = M[bt*PIX + (e % PIX)];
  out[g] = I[g]*(1.f - m) + a*m;
}

__global__ __launch_bounds__(256) void kfinal(const float* __restrict__ I,
                                              const float* __restrict__ M,
                                              float* __restrict__ out){
  int g = blockIdx.x*256 + threadIdx.x;
  if (g >= BTC*EPIX) return;
  int bt = g / EPIX, e = g % EPIX;
  float a = out[g];
  float m = M[bt*PIX + (e % PIX)];
  out[g] = I[g]*(1.f - m) + a*m;
}

extern "C" void kernel_launch(void* const* d_in, const int* in_sizes, int n_in,
                              void* d_out, int out_size, void* d_ws, size_t ws_size,
                              hipStream_t stream){
  const float* I = (const float*)d_in[0];
  const float* S = (const float*)d_in[1];
  const float* M = (const float*)d_in[2];
  float* out = (float*)d_out;

  const size_t needScr = (size_t)NB*EPIX*sizeof(f16);   // 20,684,160 B
  const size_t needSt  = (size_t)NB*PIX*sizeof(f16);    //  6,894,720 B

  bool useScr = ws_size >= needScr;
  bool useSt;
  f16* scr = (f16*)d_ws;
  f16* St;
  if (useScr){
    useSt = ws_size >= needScr + needSt;
    St = (f16*)((char*)d_ws + needScr);
  } else {
    useSt = ws_size >= needSt;
    St = (f16*)d_ws;
  }

  if (useSt) ktrans<<<BTC*102, 256, 0, stream>>>(S, St);

  if (useScr){
    if (useSt) kmain<true ,true ><<<NB, 256, 0, stream>>>(I, S, M, St, scr, out);
    else       kmain<true ,false><<<NB, 256, 0, stream>>>(I, S, M, St, scr, out);
    kreduce<<<(BTC*EPIX + 255)/256, 256, 0, stream>>>(I, M, scr, out);
  } else {
    hipMemsetAsync(out, 0, (size_t)BTC*EPIX*sizeof(float), stream);
    if (useSt) kmain<false,true ><<<NB, 256, 0, stream>>>(I, S, M, St, scr, out);
    else       kmain<false,false><<<NB, 256, 0, stream>>>(I, S, M, St, scr, out);
    kfinal<<<(BTC*EPIX + 255)/256, 256, 0, stream>>>(I, M, out);
  }
}

// Round 3
// 117.205 us; speedup vs baseline: 1.2051x; 1.2051x over previous
//
#include <hip/hip_runtime.h>

#define NL 133
#define HT 60
#define WD 108
#define PIX (HT*WD)          // 6480
#define CT 432               // 3*12*12 channels after unfold
#define L45 45               // patches
#define STR 440              // LDS row stride in halves (880B: 16B-aligned, 2-way bank-free)
#define BTC 4
#define NB (BTC*NL)          // 532 blocks
#define EPIX (3*PIX)         // 19440 elements per (bt) image

typedef _Float16 f16;
typedef _Float16 h4v __attribute__((ext_vector_type(4)));
typedef _Float16 h8v __attribute__((ext_vector_type(8)));
typedef float f32x4 __attribute__((ext_vector_type(4)));

__device__ __forceinline__ f32x4 mfma_k32(h8v a, h8v b, f32x4 c){
  return __builtin_amdgcn_mfma_f32_16x16x32_f16(a, b, c, 0, 0, 0);
}
__device__ __forceinline__ f32x4 mfma_k16(h4v a, h4v b, f32x4 c){
  return __builtin_amdgcn_mfma_f32_16x16x16f16(a, b, c, 0, 0, 0);
}

// ---- S transpose: (bt, pix, n) f32 -> (bt*133+n, pix) f16 ----
__global__ __launch_bounds__(256) void ktrans(const float* __restrict__ S,
                                              f16* __restrict__ St){
  __shared__ float tile[64][135];
  int blk = blockIdx.x;
  int bt = blk / 102, t = blk % 102;
  int pix0 = t * 64;
  int tid = threadIdx.x;
  for (int r = tid; r < 64*NL; r += 256){
    int p = r / NL, nn = r % NL;
    int pix = pix0 + p;
    if (pix < PIX) tile[p][nn] = S[((size_t)bt*PIX + pix)*NL + nn];
  }
  __syncthreads();
  for (int w = tid; w < 64*NL; w += 256){
    int nn = w / 64, p = w % 64;
    int pix = pix0 + p;
    if (pix < PIX) St[((size_t)(bt*NL + nn))*PIX + pix] = (f16)tile[p][nn];
  }
}

// ---- main: per (bt,n): build U,Kt in LDS; GEMM1 (MFMA) Wm = U*Kt^T; L1 norm;
//      GEMM2 (MFMA) D = Wm * Kt; store per-layer (scr) or atomic ----
template<bool USE_SCR, bool USE_ST>
__global__ __launch_bounds__(256) void kmain(const float* __restrict__ I,
                                             const float* __restrict__ S,
                                             const float* __restrict__ M,
                                             const f16* __restrict__ St,
                                             f16* __restrict__ scr,
                                             float* __restrict__ outAcc){
  // combined LDS: bufU = rows [0,45), bufK = rows [45,93) of stride-440 f16.
  // bufK rows 45..47 (i.e. lds rows 90..92) are zeroed for the GEMM K-tails.
  __shared__ f16 lds[(L45 + 48)*STR];           // 81,840 B -> 2 blocks/CU
  f16* bufU = lds;
  f16* bufK = lds + L45*STR;

  int b  = blockIdx.x;
  int bt = b / NL, n = b % NL;
  int tid = threadIdx.x;
  const float* Ib = I + (size_t)bt*EPIX;
  const float* Mb = M + (size_t)bt*PIX;

  // zero bufK rows 45..47
  for (int z = tid; z < 3*STR; z += 256) bufK[L45*STR + z] = (f16)0.f;

  // Phase A: build U/Kt tiles. thread <-> channel c; loop over 45 patches.
  for (int c = tid; c < CT; c += 256){
    int ch = c / 144, kr = c % 144;
    int ky = kr / 12, kx = kr % 12;
    const float* Ich = Ib + ch*PIX;
    int p = 0;
    #pragma unroll
    for (int py = 0; py < 5; ++py){
      int row = (py*12 + ky)*WD;
      #pragma unroll
      for (int px = 0; px < 9; ++px, ++p){
        int x = px*12 + kx;
        float sv;
        if (USE_ST) sv = (float)St[(size_t)b*PIX + row + x];
        else        sv = S[((size_t)bt*PIX + row + x)*NL + n];
        float iv = Ich[row + x];
        float mv = Mb[row + x];
        float v = iv * sv;
        float u = v * mv;
        bufU[p*STR + c] = (f16)u;
        bufK[p*STR + c] = (f16)(v - u);
      }
    }
  }
  __syncthreads();

  // ---- GEMM1: Wm(p,q) = sum_c U(p,c)*Kt(q,c).  9 16x16 tiles, 3 slots/wave.
  int wid  = tid >> 6;
  int lane = tid & 63;
  int lrow = lane & 15, lgrp = lane >> 4;

  f32x4 acc0 = {0.f,0.f,0.f,0.f}, acc1 = acc0, acc2 = acc0;
  // tile ids (clamped; duplicates write identical data)
  int t0 = wid;                 // 0..3
  int t1 = wid + 4;             // 4..7
  int t2 = (wid + 8 < 9) ? wid + 8 : 8;   // 8 (wave0) else dup tile 8
  int ti0 = t0/3, tj0 = t0%3;
  int ti1 = t1/3, tj1 = t1%3;
  int ti2 = t2/3, tj2 = t2%3;

  const f16* uA0 = &bufU[(ti0*16 + lrow)*STR];
  const f16* uA1 = &bufU[(ti1*16 + lrow)*STR];
  const f16* uA2 = &bufU[(ti2*16 + lrow)*STR];
  const f16* kB0 = &bufK[(tj0*16 + lrow)*STR];
  const f16* kB1 = &bufK[(tj1*16 + lrow)*STR];
  const f16* kB2 = &bufK[(tj2*16 + lrow)*STR];

  for (int ks = 0; ks < 13; ++ks){
    int c0 = ks*32 + lgrp*8;
    h8v a0 = *(const h8v*)&uA0[c0];
    h8v a1 = *(const h8v*)&uA1[c0];
    h8v a2 = *(const h8v*)&uA2[c0];
    h8v b0 = *(const h8v*)&kB0[c0];
    h8v b1 = *(const h8v*)&kB1[c0];
    h8v b2 = *(const h8v*)&kB2[c0];
    acc0 = mfma_k32(a0, b0, acc0);
    acc1 = mfma_k32(a1, b1, acc1);
    acc2 = mfma_k32(a2, b2, acc2);
  }
  { // K-tail c in [416,432)
    int c0 = 416 + lgrp*4;
    h4v a0 = *(const h4v*)&uA0[c0];
    h4v a1 = *(const h4v*)&uA1[c0];
    h4v a2 = *(const h4v*)&uA2[c0];
    h4v b0 = *(const h4v*)&kB0[c0];
    h4v b1 = *(const h4v*)&kB1[c0];
    h4v b2 = *(const h4v*)&kB2[c0];
    acc0 = mfma_k16(a0, b0, acc0);
    acc1 = mfma_k16(a1, b1, acc1);
    acc2 = mfma_k16(a2, b2, acc2);
  }
  __syncthreads();   // all GEMM1 LDS reads done before overlaying bufU

  // ---- stage raw Wm (f32) + normalized Wm (f16) over dead bufU
  float* Wm32 = (float*)lds;                       // [48][49]
  f16*   Wm16 = (f16*)((char*)lds + 48*49*4);      // [48][48], 16B-aligned
  {
    #pragma unroll
    for (int r = 0; r < 4; ++r){
      Wm32[(ti0*16 + lgrp*4 + r)*49 + tj0*16 + lrow] = acc0[r];
      Wm32[(ti1*16 + lgrp*4 + r)*49 + tj1*16 + lrow] = acc1[r];
      Wm32[(ti2*16 + lgrp*4 + r)*49 + tj2*16 + lrow] = acc2[r];
    }
  }
  __syncthreads();

  if (tid < L45){
    float rs = 0.f;
    for (int q = 0; q < L45; ++q) rs += fabsf(Wm32[tid*49 + q]);
    float inv = 1.0f / fmaxf(rs, 1e-12f);
    for (int j = 0; j < 48; ++j)
      Wm16[tid*48 + j] = (j < L45) ? (f16)(Wm32[tid*49 + j]*inv) : (f16)0.f;
  }
  __syncthreads();

  // ---- GEMM2: D(i,c) = sum_j Wm(i,j)*Kt(j,c). 3 i-tiles x 27 c-tiles.
  h8v aw0 = *(const h8v*)&Wm16[( 0 + lrow)*48 + lgrp*8];
  h8v aw1 = *(const h8v*)&Wm16[(16 + lrow)*48 + lgrp*8];
  h8v aw2 = *(const h8v*)&Wm16[(32 + lrow)*48 + lgrp*8];
  h4v at0 = *(const h4v*)&Wm16[( 0 + lrow)*48 + 32 + lgrp*4];
  h4v at1 = *(const h4v*)&Wm16[(16 + lrow)*48 + 32 + lgrp*4];
  h4v at2 = *(const h4v*)&Wm16[(32 + lrow)*48 + 32 + lgrp*4];

  for (int cb = wid; cb < 27; cb += 4){
    int cbase = cb*16 + lrow;
    h8v bK; h4v bT;
    #pragma unroll
    for (int r = 0; r < 8; ++r) bK[r] = bufK[(lgrp*8 + r)*STR + cbase];
    #pragma unroll
    for (int r = 0; r < 4; ++r) bT[r] = bufK[(32 + lgrp*4 + r)*STR + cbase];

    int ch  = cb / 9;                 // c-block fully inside one channel
    int kr  = (cb % 9)*16 + lrow;
    int ky  = kr / 12, kx = kr - ky*12;
    int pixc = ch*PIX + ky*WD + kx;

    f32x4 d0 = {0.f,0.f,0.f,0.f}, d1 = d0, d2 = d0;
    d0 = mfma_k32(aw0, bK, d0);  d0 = mfma_k16(at0, bT, d0);
    d1 = mfma_k32(aw1, bK, d1);  d1 = mfma_k16(at1, bT, d1);
    d2 = mfma_k32(aw2, bK, d2);  d2 = mfma_k16(at2, bT, d2);

    #pragma unroll
    for (int r = 0; r < 4; ++r){
      { int i = 0 + lgrp*4 + r;
        int iy = i/9, ix = i - iy*9;
        int pix = pixc + (iy*12)*WD + ix*12;
        if (USE_SCR) scr[(size_t)b*EPIX + pix] = (f16)d0[r];
        else atomicAdd(&outAcc[(size_t)bt*EPIX + pix], (float)d0[r]); }
      { int i = 16 + lgrp*4 + r;
        int iy = i/9, ix = i - iy*9;
        int pix = pixc + (iy*12)*WD + ix*12;
        if (USE_SCR) scr[(size_t)b*EPIX + pix] = (f16)d1[r];
        else atomicAdd(&outAcc[(size_t)bt*EPIX + pix], (float)d1[r]); }
      { int i = 32 + lgrp*4 + r;
        if (i < L45){
          int iy = i/9, ix = i - iy*9;
          int pix = pixc + (iy*12)*WD + ix*12;
          if (USE_SCR) scr[(size_t)b*EPIX + pix] = (f16)d2[r];
          else atomicAdd(&outAcc[(size_t)bt*EPIX + pix], (float)d2[r]); } }
    }
  }
}

// ---- reduce over layers + final blend (vectorized x4) ----
__global__ __launch_bounds__(256) void kreduce(const float* __restrict__ I,
                                               const float* __restrict__ M,
                                               const f16* __restrict__ scr,
                                               float* __restrict__ out){
  int g = blockIdx.x*256 + threadIdx.x;          // one thread per 4 elements
  if (g >= BTC*EPIX/4) return;
  int e4 = g*4;
  int bt = e4 / EPIX, e = e4 % EPIX;
  const f16* p = scr + (size_t)bt*NL*EPIX + e;
  float a0=0.f, a1=0.f, a2=0.f, a3=0.f;
  for (int nn = 0; nn < NL; ++nn){
    h4v v = *(const h4v*)&p[(size_t)nn*EPIX];
    a0 += (float)v[0]; a1 += (float)v[1]; a2 += (float)v[2]; a3 += (float)v[3];
  }
  int pixb = e % PIX;                            // e..e+3 stay in one channel
  const float* Mb = M + (size_t)bt*PIX;
  float4 iv = *(const float4*)&I[e4];
  float m0 = Mb[pixb], m1 = Mb[pixb+1], m2 = Mb[pixb+2], m3 = Mb[pixb+3];
  float4 o;
  o.x = iv.x*(1.f-m0) + a0*m0;
  o.y = iv.y*(1.f-m1) + a1*m1;
  o.z = iv.z*(1.f-m2) + a2*m2;
  o.w = iv.w*(1.f-m3) + a3*m3;
  *(float4*)&out[e4] = o;
}

__global__ __launch_bounds__(256) void kfinal(const float* __restrict__ I,
                                              const float* __restrict__ M,
                                              float* __restrict__ out){
  int g = blockIdx.x*256 + threadIdx.x;
  if (g >= BTC*EPIX) return;
  int bt = g / EPIX, e = g % EPIX;
  float a = out[g];
  float m = M[bt*PIX + (e % PIX)];
  out[g] = I[g]*(1.f - m) + a*m;
}

extern "C" void kernel_launch(void* const* d_in, const int* in_sizes, int n_in,
                              void* d_out, int out_size, void* d_ws, size_t ws_size,
                              hipStream_t stream){
  const float* I = (const float*)d_in[0];
  const float* S = (const float*)d_in[1];
  const float* M = (const float*)d_in[2];
  float* out = (float*)d_out;

  const size_t needScr = (size_t)NB*EPIX*sizeof(f16);   // 20,684,160 B
  const size_t needSt  = (size_t)NB*PIX*sizeof(f16);    //  6,894,720 B

  bool useScr = ws_size >= needScr;
  bool useSt;
  f16* scr = (f16*)d_ws;
  f16* St;
  if (useScr){
    useSt = ws_size >= needScr + needSt;
    St = (f16*)((char*)d_ws + needScr);
  } else {
    useSt = ws_size >= needSt;
    St = (f16*)d_ws;
  }

  if (useSt) ktrans<<<BTC*102, 256, 0, stream>>>(S, St);

  if (useScr){
    if (useSt) kmain<true ,true ><<<NB, 256, 0, stream>>>(I, S, M, St, scr, out);
    else       kmain<true ,false><<<NB, 256, 0, stream>>>(I, S, M, St, scr, out);
    kreduce<<<(BTC*EPIX/4 + 255)/256, 256, 0, stream>>>(I, M, scr, out);
  } else {
    (void)hipMemsetAsync(out, 0, (size_t)BTC*EPIX*sizeof(float), stream);
    if (useSt) kmain<false,true ><<<NB, 256, 0, stream>>>(I, S, M, St, scr, out);
    else       kmain<false,false><<<NB, 256, 0, stream>>>(I, S, M, St, scr, out);
    kfinal<<<(BTC*EPIX + 255)/256, 256, 0, stream>>>(I, M, out);
  }
}

// Round 4
// 113.780 us; speedup vs baseline: 1.2414x; 1.0301x over previous
//
#include <hip/hip_runtime.h>

#define NL 133
#define HT 60
#define WD 108
#define PIX (HT*WD)          // 6480
#define CT 432               // 3*12*12 channels after unfold
#define L45 45               // patches
#define STR 440              // LDS row stride in halves (880B: 16B-aligned)
#define BTC 4
#define NB (BTC*NL)          // 532 blocks
#define EPIX (3*PIX)         // 19440 elements per (bt) image

typedef _Float16 f16;
typedef _Float16 h4v __attribute__((ext_vector_type(4)));
typedef _Float16 h8v __attribute__((ext_vector_type(8)));
typedef float f32x4 __attribute__((ext_vector_type(4)));

__device__ __forceinline__ f32x4 mfma_k32(h8v a, h8v b, f32x4 c){
  return __builtin_amdgcn_mfma_f32_16x16x32_f16(a, b, c, 0, 0, 0);
}
__device__ __forceinline__ f32x4 mfma_k16(h4v a, h4v b, f32x4 c){
  return __builtin_amdgcn_mfma_f32_16x16x16f16(a, b, c, 0, 0, 0);
}

// ---- prep: blocks [0,408): S transpose+unfold -> Su[b][p][kr] f16
//            blocks [408,588): IMu/IKu[bt][p][c] = unfold(I*M), unfold(I*(1-M)) f16
__global__ __launch_bounds__(256) void kprep(const float* __restrict__ S,
                                             const float* __restrict__ I,
                                             const float* __restrict__ M,
                                             f16* __restrict__ Su,
                                             f16* __restrict__ IMu,
                                             f16* __restrict__ IKu){
  __shared__ float tile[64][135];
  int blk = blockIdx.x;
  int tid = threadIdx.x;
  if (blk < BTC*102){
    int bt = blk / 102, t = blk % 102;
    int pix0 = t * 64;
    for (int r = tid; r < 64*NL; r += 256){
      int p = r / NL, nn = r % NL;
      int pix = pix0 + p;
      if (pix < PIX) tile[p][nn] = S[((size_t)bt*PIX + pix)*NL + nn];
    }
    __syncthreads();
    for (int w = tid; w < 64*NL; w += 256){
      int nn = w / 64, pp = w % 64;
      int pix = pix0 + pp;
      if (pix < PIX){
        int y = pix / WD, x = pix % WD;
        int py = y/12, ky = y%12, px = x/12, kx = x%12;
        int pa = py*9 + px, kr = ky*12 + kx;
        Su[(size_t)(bt*NL + nn)*PIX + pa*144 + kr] = (f16)tile[pp][nn];
      }
    }
  } else {
    int b2 = blk - BTC*102;            // (bt, patch)
    int bt = b2 / L45, pa = b2 % L45;
    int py = pa/9, px = pa%9;
    const float* Ib = I + (size_t)bt*EPIX;
    const float* Mb = M + (size_t)bt*PIX;
    for (int c = tid; c < CT; c += 256){
      int ch = c/144, kr = c%144;
      int ky = kr/12, kx = kr%12;
      int pix = (py*12 + ky)*WD + px*12 + kx;
      float iv = Ib[ch*PIX + pix];
      float mv = Mb[pix];
      IMu[((size_t)bt*L45 + pa)*CT + c] = (f16)(iv*mv);
      IKu[((size_t)bt*L45 + pa)*CT + c] = (f16)(iv*(1.f - mv));
    }
  }
}

// ---- main: per (bt,n): build U,Kt in LDS (vectorized); GEMM1 (MFMA) Wm = U*Kt^T;
//      L1 norm; GEMM2 (MFMA) D = Wm * Kt; store per-layer (scr) or atomic ----
template<bool USE_SCR>
__global__ __launch_bounds__(256) void kmain(const f16* __restrict__ IMu,
                                             const f16* __restrict__ IKu,
                                             const f16* __restrict__ Su,
                                             f16* __restrict__ scr,
                                             float* __restrict__ outAcc){
  __shared__ f16 lds[(L45 + 48)*STR];           // 81,840 B -> 2 blocks/CU
  f16* bufU = lds;
  f16* bufK = lds + L45*STR;

  int b  = blockIdx.x;
  int bt = b / NL;
  int tid = threadIdx.x;

  // zero bufK rows 45..47 (K-tail contracts against zeros)
  for (int z = tid; z < 3*STR; z += 256) bufK[L45*STR + z] = (f16)0.f;

  // Phase A: bufU[p][c] = IMu[p][c]*Su[p][c%144]; bufK[p][c] = IKu[p][c]*Su[...]
  {
    const f16* IMb = IMu + (size_t)bt*L45*CT;
    const f16* IKb = IKu + (size_t)bt*L45*CT;
    const f16* Sb  = Su  + (size_t)b*PIX;
    for (int slot = tid; slot < L45*54; slot += 256){
      int p = slot / 54, cg = slot % 54;
      int c0 = cg*8;
      h8v im = *(const h8v*)&IMb[p*CT + c0];
      h8v ik = *(const h8v*)&IKb[p*CT + c0];
      h8v sv = *(const h8v*)&Sb[p*144 + (c0 % 144)];
      *(h8v*)&bufU[p*STR + c0] = im*sv;
      *(h8v*)&bufK[p*STR + c0] = ik*sv;
    }
  }
  __syncthreads();

  // ---- GEMM1: Wm(p,q) = sum_c U(p,c)*Kt(q,c).  9 16x16 tiles, 3 slots/wave.
  int wid  = tid >> 6;
  int lane = tid & 63;
  int lrow = lane & 15, lgrp = lane >> 4;

  f32x4 acc0 = {0.f,0.f,0.f,0.f}, acc1 = acc0, acc2 = acc0;
  int t0 = wid;
  int t1 = wid + 4;
  int t2 = (wid + 8 < 9) ? wid + 8 : 8;
  int ti0 = t0/3, tj0 = t0%3;
  int ti1 = t1/3, tj1 = t1%3;
  int ti2 = t2/3, tj2 = t2%3;

  const f16* uA0 = &bufU[(ti0*16 + lrow)*STR];
  const f16* uA1 = &bufU[(ti1*16 + lrow)*STR];
  const f16* uA2 = &bufU[(ti2*16 + lrow)*STR];
  const f16* kB0 = &bufK[(tj0*16 + lrow)*STR];
  const f16* kB1 = &bufK[(tj1*16 + lrow)*STR];
  const f16* kB2 = &bufK[(tj2*16 + lrow)*STR];

  for (int ks = 0; ks < 13; ++ks){
    int c0 = ks*32 + lgrp*8;
    h8v a0 = *(const h8v*)&uA0[c0];
    h8v a1 = *(const h8v*)&uA1[c0];
    h8v a2 = *(const h8v*)&uA2[c0];
    h8v b0 = *(const h8v*)&kB0[c0];
    h8v b1 = *(const h8v*)&kB1[c0];
    h8v b2 = *(const h8v*)&kB2[c0];
    acc0 = mfma_k32(a0, b0, acc0);
    acc1 = mfma_k32(a1, b1, acc1);
    acc2 = mfma_k32(a2, b2, acc2);
  }
  { // K-tail c in [416,432)
    int c0 = 416 + lgrp*4;
    h4v a0 = *(const h4v*)&uA0[c0];
    h4v a1 = *(const h4v*)&uA1[c0];
    h4v a2 = *(const h4v*)&uA2[c0];
    h4v b0 = *(const h4v*)&kB0[c0];
    h4v b1 = *(const h4v*)&kB1[c0];
    h4v b2 = *(const h4v*)&kB2[c0];
    acc0 = mfma_k16(a0, b0, acc0);
    acc1 = mfma_k16(a1, b1, acc1);
    acc2 = mfma_k16(a2, b2, acc2);
  }
  __syncthreads();

  // ---- stage raw Wm (f32) + normalized Wm (f16) over dead bufU
  float* Wm32 = (float*)lds;                       // [48][49]
  f16*   Wm16 = (f16*)((char*)lds + 48*49*4);      // [48][48]
  {
    #pragma unroll
    for (int r = 0; r < 4; ++r){
      Wm32[(ti0*16 + lgrp*4 + r)*49 + tj0*16 + lrow] = acc0[r];
      Wm32[(ti1*16 + lgrp*4 + r)*49 + tj1*16 + lrow] = acc1[r];
      Wm32[(ti2*16 + lgrp*4 + r)*49 + tj2*16 + lrow] = acc2[r];
    }
  }
  __syncthreads();

  if (tid < L45){
    float rs = 0.f;
    for (int q = 0; q < L45; ++q) rs += fabsf(Wm32[tid*49 + q]);
    float inv = 1.0f / fmaxf(rs, 1e-12f);
    for (int j = 0; j < 48; ++j)
      Wm16[tid*48 + j] = (j < L45) ? (f16)(Wm32[tid*49 + j]*inv) : (f16)0.f;
  }
  __syncthreads();

  // ---- GEMM2: D(i,c) = sum_j Wm(i,j)*Kt(j,c). 3 i-tiles x 27 c-tiles.
  h8v aw0 = *(const h8v*)&Wm16[( 0 + lrow)*48 + lgrp*8];
  h8v aw1 = *(const h8v*)&Wm16[(16 + lrow)*48 + lgrp*8];
  h8v aw2 = *(const h8v*)&Wm16[(32 + lrow)*48 + lgrp*8];
  h4v at0 = *(const h4v*)&Wm16[( 0 + lrow)*48 + 32 + lgrp*4];
  h4v at1 = *(const h4v*)&Wm16[(16 + lrow)*48 + 32 + lgrp*4];
  h4v at2 = *(const h4v*)&Wm16[(32 + lrow)*48 + 32 + lgrp*4];

  for (int cb = wid; cb < 27; cb += 4){
    int cbase = cb*16 + lrow;
    h8v bK; h4v bT;
    #pragma unroll
    for (int r = 0; r < 8; ++r) bK[r] = bufK[(lgrp*8 + r)*STR + cbase];
    #pragma unroll
    for (int r = 0; r < 4; ++r) bT[r] = bufK[(32 + lgrp*4 + r)*STR + cbase];

    int ch  = cb / 9;
    int kr  = (cb % 9)*16 + lrow;
    int ky  = kr / 12, kx = kr - ky*12;
    int pixc = ch*PIX + ky*WD + kx;

    f32x4 d0 = {0.f,0.f,0.f,0.f}, d1 = d0, d2 = d0;
    d0 = mfma_k32(aw0, bK, d0);  d0 = mfma_k16(at0, bT, d0);
    d1 = mfma_k32(aw1, bK, d1);  d1 = mfma_k16(at1, bT, d1);
    d2 = mfma_k32(aw2, bK, d2);  d2 = mfma_k16(at2, bT, d2);

    #pragma unroll
    for (int r = 0; r < 4; ++r){
      { int i = 0 + lgrp*4 + r;
        int iy = i/9, ix = i - iy*9;
        int pix = pixc + (iy*12)*WD + ix*12;
        if (USE_SCR) scr[(size_t)b*EPIX + pix] = (f16)d0[r];
        else atomicAdd(&outAcc[(size_t)bt*EPIX + pix], (float)d0[r]); }
      { int i = 16 + lgrp*4 + r;
        int iy = i/9, ix = i - iy*9;
        int pix = pixc + (iy*12)*WD + ix*12;
        if (USE_SCR) scr[(size_t)b*EPIX + pix] = (f16)d1[r];
        else atomicAdd(&outAcc[(size_t)bt*EPIX + pix], (float)d1[r]); }
      { int i = 32 + lgrp*4 + r;
        if (i < L45){
          int iy = i/9, ix = i - iy*9;
          int pix = pixc + (iy*12)*WD + ix*12;
          if (USE_SCR) scr[(size_t)b*EPIX + pix] = (f16)d2[r];
          else atomicAdd(&outAcc[(size_t)bt*EPIX + pix], (float)d2[r]); } }
    }
  }
}

// ---- reduce over layers + final blend; 8 threads per float4-group ----
__global__ __launch_bounds__(256) void kreduce(const float* __restrict__ I,
                                               const float* __restrict__ M,
                                               const f16* __restrict__ scr,
                                               float* __restrict__ out){
  int t = blockIdx.x*256 + threadIdx.x;
  int sub = t & 7, g = t >> 3;
  if (g >= BTC*EPIX/4) return;
  int e4 = g*4;
  int bt = e4 / EPIX, e = e4 % EPIX;
  const f16* p = scr + (size_t)bt*NL*EPIX + e;
  float a0=0.f, a1=0.f, a2=0.f, a3=0.f;
  for (int nn = sub; nn < NL; nn += 8){
    h4v v = *(const h4v*)&p[(size_t)nn*EPIX];
    a0 += (float)v[0]; a1 += (float)v[1]; a2 += (float)v[2]; a3 += (float)v[3];
  }
  #pragma unroll
  for (int s = 1; s < 8; s <<= 1){
    a0 += __shfl_xor(a0, s); a1 += __shfl_xor(a1, s);
    a2 += __shfl_xor(a2, s); a3 += __shfl_xor(a3, s);
  }
  if (sub == 0){
    int pixb = e % PIX;
    const float* Mb = M + (size_t)bt*PIX;
    float4 iv = *(const float4*)&I[e4];
    float m0 = Mb[pixb], m1 = Mb[pixb+1], m2 = Mb[pixb+2], m3 = Mb[pixb+3];
    float4 o;
    o.x = iv.x*(1.f-m0) + a0*m0;
    o.y = iv.y*(1.f-m1) + a1*m1;
    o.z = iv.z*(1.f-m2) + a2*m2;
    o.w = iv.w*(1.f-m3) + a3*m3;
    *(float4*)&out[e4] = o;
  }
}

__global__ __launch_bounds__(256) void kfinal(const float* __restrict__ I,
                                              const float* __restrict__ M,
                                              float* __restrict__ out){
  int g = blockIdx.x*256 + threadIdx.x;
  if (g >= BTC*EPIX) return;
  int bt = g / EPIX, e = g % EPIX;
  float a = out[g];
  float m = M[bt*PIX + (e % PIX)];
  out[g] = I[g]*(1.f - m) + a*m;
}

extern "C" void kernel_launch(void* const* d_in, const int* in_sizes, int n_in,
                              void* d_out, int out_size, void* d_ws, size_t ws_size,
                              hipStream_t stream){
  const float* I = (const float*)d_in[0];
  const float* S = (const float*)d_in[1];
  const float* M = (const float*)d_in[2];
  float* out = (float*)d_out;

  const size_t needSu  = (size_t)NB*PIX*sizeof(f16);      //  6,894,720 B
  const size_t needIM  = (size_t)BTC*L45*CT*sizeof(f16);  //    155,520 B each
  const size_t needScr = (size_t)NB*EPIX*sizeof(f16);     // 20,684,160 B
  const size_t prepSz  = needSu + 2*needIM;               //  7,205,760 B

  f16* Su  = (f16*)d_ws;
  f16* IMu = (f16*)((char*)d_ws + needSu);
  f16* IKu = (f16*)((char*)d_ws + needSu + needIM);
  f16* scr = (f16*)((char*)d_ws + prepSz);
  bool useScr = ws_size >= prepSz + needScr;              // observed ws: 268 MB

  kprep<<<BTC*102 + BTC*L45, 256, 0, stream>>>(S, I, M, Su, IMu, IKu);

  if (useScr){
    kmain<true ><<<NB, 256, 0, stream>>>(IMu, IKu, Su, scr, out);
    kreduce<<<((BTC*EPIX/4)*8 + 255)/256, 256, 0, stream>>>(I, M, scr, out);
  } else {
    (void)hipMemsetAsync(out, 0, (size_t)BTC*EPIX*sizeof(float), stream);
    kmain<false><<<NB, 256, 0, stream>>>(IMu, IKu, Su, scr, out);
    kfinal<<<(BTC*EPIX + 255)/256, 256, 0, stream>>>(I, M, out);
  }
}

// Round 7
// 111.182 us; speedup vs baseline: 1.2704x; 1.0234x over previous
//
#include <hip/hip_runtime.h>

#define NL 133
#define HT 60
#define WD 108
#define PIX (HT*WD)          // 6480
#define CT 432               // 3*12*12 channels after unfold
#define L45 45               // patches
#define STR 440              // LDS row stride in halves (880B)
#define BTC 4
#define NB (BTC*NL)          // 532
#define EPIX (3*PIX)         // 19440

typedef _Float16 f16;
typedef _Float16 h4v __attribute__((ext_vector_type(4)));
typedef _Float16 h8v __attribute__((ext_vector_type(8)));
typedef float f32x4 __attribute__((ext_vector_type(4)));

__device__ __forceinline__ f32x4 mfma_k32(h8v a, h8v b, f32x4 c){
  return __builtin_amdgcn_mfma_f32_16x16x32_f16(a, b, c, 0, 0, 0);
}
__device__ __forceinline__ f32x4 mfma_k16(h4v a, h4v b, f32x4 c){
  return __builtin_amdgcn_mfma_f32_16x16x16f16(a, b, c, 0, 0, 0);
}

// ---- kprep (round-4 verbatim): blocks [0,408): S transpose+unfold -> Su[b][pa*144+kr]
//      blocks [408,588): IMu/IKu[bt][pa][c] = unfold(I*M), unfold(I*(1-M)) f16
__global__ __launch_bounds__(256) void kprep(const float* __restrict__ S,
                                             const float* __restrict__ I,
                                             const float* __restrict__ M,
                                             f16* __restrict__ Su,
                                             f16* __restrict__ IMu,
                                             f16* __restrict__ IKu){
  __shared__ float tile[64][135];
  int blk = blockIdx.x;
  int tid = threadIdx.x;
  if (blk < BTC*102){
    int bt = blk / 102, t = blk % 102;
    int pix0 = t * 64;
    for (int r = tid; r < 64*NL; r += 256){
      int p = r / NL, nn = r % NL;
      int pix = pix0 + p;
      if (pix < PIX) tile[p][nn] = S[((size_t)bt*PIX + pix)*NL + nn];
    }
    __syncthreads();
    for (int w = tid; w < 64*NL; w += 256){
      int nn = w / 64, pp = w % 64;
      int pix = pix0 + pp;
      if (pix < PIX){
        int y = pix / WD, x = pix % WD;
        int py = y/12, ky = y%12, px = x/12, kx = x%12;
        int pa = py*9 + px, kr = ky*12 + kx;
        Su[(size_t)(bt*NL + nn)*PIX + pa*144 + kr] = (f16)tile[pp][nn];
      }
    }
  } else {
    int b2 = blk - BTC*102;            // (bt, patch)
    int bt = b2 / L45, pa = b2 % L45;
    int py = pa/9, px = pa%9;
    const float* Ib = I + (size_t)bt*EPIX;
    const float* Mb = M + (size_t)bt*PIX;
    for (int c = tid; c < CT; c += 256){
      int ch = c/144, kr = c%144;
      int ky = kr/12, kx = kr%12;
      int pix = (py*12 + ky)*WD + px*12 + kx;
      float iv = Ib[ch*PIX + pix];
      float mv = Mb[pix];
      IMu[((size_t)bt*L45 + pa)*CT + c] = (f16)(iv*mv);
      IKu[((size_t)bt*L45 + pa)*CT + c] = (f16)(iv*(1.f - mv));
    }
  }
}

// ---- kmain (round-4 verbatim EXCEPT the USE_SCR store uses [b][pa][c] layout) ----
template<bool USE_SCR>
__global__ __launch_bounds__(256) void kmain(const f16* __restrict__ IMu,
                                             const f16* __restrict__ IKu,
                                             const f16* __restrict__ Su,
                                             f16* __restrict__ scr,
                                             float* __restrict__ outAcc){
  __shared__ f16 lds[(L45 + 48)*STR];           // 81,840 B -> 2 blocks/CU
  f16* bufU = lds;
  f16* bufK = lds + L45*STR;

  int b  = blockIdx.x;
  int bt = b / NL;
  int tid = threadIdx.x;

  // zero bufK rows 45..47 (K-tail contracts against zeros)
  for (int z = tid; z < 3*STR; z += 256) bufK[L45*STR + z] = (f16)0.f;

  // Phase A: bufU[p][c] = IMu[p][c]*Su[p][c%144]; bufK[p][c] = IKu[p][c]*Su[...]
  {
    const f16* IMb = IMu + (size_t)bt*L45*CT;
    const f16* IKb = IKu + (size_t)bt*L45*CT;
    const f16* Sb  = Su  + (size_t)b*PIX;
    for (int slot = tid; slot < L45*54; slot += 256){
      int p = slot / 54, cg = slot % 54;
      int c0 = cg*8;
      h8v im = *(const h8v*)&IMb[p*CT + c0];
      h8v ik = *(const h8v*)&IKb[p*CT + c0];
      h8v sv = *(const h8v*)&Sb[p*144 + (c0 % 144)];
      *(h8v*)&bufU[p*STR + c0] = im*sv;
      *(h8v*)&bufK[p*STR + c0] = ik*sv;
    }
  }
  __syncthreads();

  // ---- GEMM1: Wm(p,q) = sum_c U(p,c)*Kt(q,c).  9 16x16 tiles, 3 slots/wave.
  int wid  = tid >> 6;
  int lane = tid & 63;
  int lrow = lane & 15, lgrp = lane >> 4;

  f32x4 acc0 = {0.f,0.f,0.f,0.f}, acc1 = acc0, acc2 = acc0;
  int t0 = wid;
  int t1 = wid + 4;
  int t2 = (wid + 8 < 9) ? wid + 8 : 8;
  int ti0 = t0/3, tj0 = t0%3;
  int ti1 = t1/3, tj1 = t1%3;
  int ti2 = t2/3, tj2 = t2%3;

  const f16* uA0 = &bufU[(ti0*16 + lrow)*STR];
  const f16* uA1 = &bufU[(ti1*16 + lrow)*STR];
  const f16* uA2 = &bufU[(ti2*16 + lrow)*STR];
  const f16* kB0 = &bufK[(tj0*16 + lrow)*STR];
  const f16* kB1 = &bufK[(tj1*16 + lrow)*STR];
  const f16* kB2 = &bufK[(tj2*16 + lrow)*STR];

  for (int ks = 0; ks < 13; ++ks){
    int c0 = ks*32 + lgrp*8;
    h8v a0 = *(const h8v*)&uA0[c0];
    h8v a1 = *(const h8v*)&uA1[c0];
    h8v a2 = *(const h8v*)&uA2[c0];
    h8v b0 = *(const h8v*)&kB0[c0];
    h8v b1 = *(const h8v*)&kB1[c0];
    h8v b2 = *(const h8v*)&kB2[c0];
    acc0 = mfma_k32(a0, b0, acc0);
    acc1 = mfma_k32(a1, b1, acc1);
    acc2 = mfma_k32(a2, b2, acc2);
  }
  { // K-tail c in [416,432)
    int c0 = 416 + lgrp*4;
    h4v a0 = *(const h4v*)&uA0[c0];
    h4v a1 = *(const h4v*)&uA1[c0];
    h4v a2 = *(const h4v*)&uA2[c0];
    h4v b0 = *(const h4v*)&kB0[c0];
    h4v b1 = *(const h4v*)&kB1[c0];
    h4v b2 = *(const h4v*)&kB2[c0];
    acc0 = mfma_k16(a0, b0, acc0);
    acc1 = mfma_k16(a1, b1, acc1);
    acc2 = mfma_k16(a2, b2, acc2);
  }
  __syncthreads();

  // ---- stage raw Wm (f32) + normalized Wm (f16) over dead bufU
  float* Wm32 = (float*)lds;                       // [48][49]
  f16*   Wm16 = (f16*)((char*)lds + 48*49*4);      // [48][48]
  {
    #pragma unroll
    for (int r = 0; r < 4; ++r){
      Wm32[(ti0*16 + lgrp*4 + r)*49 + tj0*16 + lrow] = acc0[r];
      Wm32[(ti1*16 + lgrp*4 + r)*49 + tj1*16 + lrow] = acc1[r];
      Wm32[(ti2*16 + lgrp*4 + r)*49 + tj2*16 + lrow] = acc2[r];
    }
  }
  __syncthreads();

  if (tid < L45){
    float rs = 0.f;
    for (int q = 0; q < L45; ++q) rs += fabsf(Wm32[tid*49 + q]);
    float inv = 1.0f / fmaxf(rs, 1e-12f);
    for (int j = 0; j < 48; ++j)
      Wm16[tid*48 + j] = (j < L45) ? (f16)(Wm32[tid*49 + j]*inv) : (f16)0.f;
  }
  __syncthreads();

  // ---- GEMM2: D(i,c) = sum_j Wm(i,j)*Kt(j,c). 3 i-tiles x 27 c-tiles.
  h8v aw0 = *(const h8v*)&Wm16[( 0 + lrow)*48 + lgrp*8];
  h8v aw1 = *(const h8v*)&Wm16[(16 + lrow)*48 + lgrp*8];
  h8v aw2 = *(const h8v*)&Wm16[(32 + lrow)*48 + lgrp*8];
  h4v at0 = *(const h4v*)&Wm16[( 0 + lrow)*48 + 32 + lgrp*4];
  h4v at1 = *(const h4v*)&Wm16[(16 + lrow)*48 + 32 + lgrp*4];
  h4v at2 = *(const h4v*)&Wm16[(32 + lrow)*48 + 32 + lgrp*4];

  f16* sb = scr + (size_t)b*L45*CT;
  for (int cb = wid; cb < 27; cb += 4){
    int cbase = cb*16 + lrow;
    h8v bK; h4v bT;
    #pragma unroll
    for (int r = 0; r < 8; ++r) bK[r] = bufK[(lgrp*8 + r)*STR + cbase];
    #pragma unroll
    for (int r = 0; r < 4; ++r) bT[r] = bufK[(32 + lgrp*4 + r)*STR + cbase];

    int ch  = cb / 9;
    int kr  = (cb % 9)*16 + lrow;
    int ky  = kr / 12, kx = kr - ky*12;
    int pixc = ch*PIX + ky*WD + kx;

    f32x4 d0 = {0.f,0.f,0.f,0.f}, d1 = d0, d2 = d0;
    d0 = mfma_k32(aw0, bK, d0);  d0 = mfma_k16(at0, bT, d0);
    d1 = mfma_k32(aw1, bK, d1);  d1 = mfma_k16(at1, bT, d1);
    d2 = mfma_k32(aw2, bK, d2);  d2 = mfma_k16(at2, bT, d2);

    #pragma unroll
    for (int r = 0; r < 4; ++r){
      { int i = 0 + lgrp*4 + r;
        if (USE_SCR) sb[(size_t)i*CT + cbase] = (f16)d0[r];
        else {
          int iy = i/9, ix = i - iy*9;
          atomicAdd(&outAcc[(size_t)bt*EPIX + pixc + (iy*12)*WD + ix*12], (float)d0[r]); } }
      { int i = 16 + lgrp*4 + r;
        if (USE_SCR) sb[(size_t)i*CT + cbase] = (f16)d1[r];
        else {
          int iy = i/9, ix = i - iy*9;
          atomicAdd(&outAcc[(size_t)bt*EPIX + pixc + (iy*12)*WD + ix*12], (float)d1[r]); } }
      { int i = 32 + lgrp*4 + r;
        if (i < L45){
          if (USE_SCR) sb[(size_t)i*CT + cbase] = (f16)d2[r];
          else {
            int iy = i/9, ix = i - iy*9;
            atomicAdd(&outAcc[(size_t)bt*EPIX + pixc + (iy*12)*WD + ix*12], (float)d2[r]); } } }
    }
  }
}

// ---- kreduce: sum over 133 layers in [b][pa][c] layout (coalesced), blend, scatter
__global__ __launch_bounds__(256) void kreduce(const float* __restrict__ I,
                                               const float* __restrict__ M,
                                               const f16* __restrict__ scr,
                                               float* __restrict__ out){
  int t = blockIdx.x*256 + threadIdx.x;
  int sub = t & 7, g = t >> 3;
  if (g >= BTC*L45*108) return;
  int bt = g / (L45*108), rem = g % (L45*108);
  int pa = rem / 108, c4 = rem % 108;
  int c0 = c4*4;
  const f16* p = scr + ((size_t)(bt*NL)*L45 + pa)*CT + c0;
  f32x4 a = {0.f,0.f,0.f,0.f};
  #pragma unroll
  for (int k = 0; k < 17; ++k){
    int nn = sub + k*8;
    int nc = nn < NL ? nn : NL-1;
    h4v v = *(const h4v*)&p[(size_t)nc*L45*CT];
    if (nn < NL){
      a[0] += (float)v[0]; a[1] += (float)v[1];
      a[2] += (float)v[2]; a[3] += (float)v[3];
    }
  }
  #pragma unroll
  for (int s = 1; s < 8; s <<= 1){
    a[0] += __shfl_xor(a[0], s); a[1] += __shfl_xor(a[1], s);
    a[2] += __shfl_xor(a[2], s); a[3] += __shfl_xor(a[3], s);
  }
  if (sub == 0){
    int ch = c0/144, kr = c0%144, ky = kr/12, kx = kr%12;
    int py = pa/9, px = pa%9;
    int pix = (py*12 + ky)*WD + px*12 + kx;
    size_t io = (size_t)bt*EPIX + ch*PIX + pix;
    float4 iv = *(const float4*)&I[io];
    float4 mv = *(const float4*)&M[(size_t)bt*PIX + pix];
    float4 o;
    o.x = iv.x*(1.f-mv.x) + a[0]*mv.x;
    o.y = iv.y*(1.f-mv.y) + a[1]*mv.y;
    o.z = iv.z*(1.f-mv.z) + a[2]*mv.z;
    o.w = iv.w*(1.f-mv.w) + a[3]*mv.w;
    *(float4*)&out[io] = o;
  }
}

__global__ __launch_bounds__(256) void kfinal(const float* __restrict__ I,
                                              const float* __restrict__ M,
                                              float* __restrict__ out){
  int g = blockIdx.x*256 + threadIdx.x;
  if (g >= BTC*EPIX) return;
  int bt = g / EPIX, e = g % EPIX;
  float a = out[g];
  float m = M[bt*PIX + (e % PIX)];
  out[g] = I[g]*(1.f - m) + a*m;
}

extern "C" void kernel_launch(void* const* d_in, const int* in_sizes, int n_in,
                              void* d_out, int out_size, void* d_ws, size_t ws_size,
                              hipStream_t stream){
  const float* I = (const float*)d_in[0];
  const float* S = (const float*)d_in[1];
  const float* M = (const float*)d_in[2];
  float* out = (float*)d_out;

  const size_t needSu  = (size_t)NB*PIX*sizeof(f16);      //  6,894,720
  const size_t needIM  = (size_t)BTC*L45*CT*sizeof(f16);  //    155,520 each
  const size_t needScr = (size_t)NB*L45*CT*sizeof(f16);   // 20,684,160
  const size_t prepSz  = needSu + 2*needIM;

  f16* Su  = (f16*)d_ws;
  f16* IMu = (f16*)((char*)d_ws + needSu);
  f16* IKu = (f16*)((char*)d_ws + needSu + needIM);
  f16* scr = (f16*)((char*)d_ws + prepSz);
  bool useScr = ws_size >= prepSz + needScr;

  kprep<<<BTC*102 + BTC*L45, 256, 0, stream>>>(S, I, M, Su, IMu, IKu);

  if (useScr){
    kmain<true ><<<NB, 256, 0, stream>>>(IMu, IKu, Su, scr, out);
    kreduce<<<((BTC*L45*108)*8 + 255)/256, 256, 0, stream>>>(I, M, scr, out);
  } else {
    (void)hipMemsetAsync(out, 0, (size_t)BTC*EPIX*sizeof(float), stream);
    kmain<false><<<NB, 256, 0, stream>>>(IMu, IKu, Su, scr, out);
    kfinal<<<(BTC*EPIX + 255)/256, 256, 0, stream>>>(I, M, out);
  }
}

// Round 9
// 111.032 us; speedup vs baseline: 1.2721x; 1.0013x over previous
//
#include <hip/hip_runtime.h>

#define NL 133
#define HT 60
#define WD 108
#define PIX (HT*WD)          // 6480
#define CT 432               // 3*12*12 channels after unfold
#define L45 45               // patches
#define STR 440              // LDS row stride in halves (880B)
#define BTC 4
#define NB (BTC*NL)          // 532
#define EPIX (3*PIX)         // 19440

typedef _Float16 f16;
typedef _Float16 h4v __attribute__((ext_vector_type(4)));
typedef _Float16 h8v __attribute__((ext_vector_type(8)));
typedef float f32x4 __attribute__((ext_vector_type(4)));

__device__ __forceinline__ f32x4 mfma_k32(h8v a, h8v b, f32x4 c){
  return __builtin_amdgcn_mfma_f32_16x16x32_f16(a, b, c, 0, 0, 0);
}
__device__ __forceinline__ f32x4 mfma_k16(h4v a, h4v b, f32x4 c){
  return __builtin_amdgcn_mfma_f32_16x16x16f16(a, b, c, 0, 0, 0);
}

// ---- kprep (round-7 verbatim): blocks [0,408): S transpose+unfold -> Su[b][pa*144+kr]
//      blocks [408,588): IMu/IKu[bt][pa][c] = unfold(I*M), unfold(I*(1-M)) f16
__global__ __launch_bounds__(256) void kprep(const float* __restrict__ S,
                                             const float* __restrict__ I,
                                             const float* __restrict__ M,
                                             f16* __restrict__ Su,
                                             f16* __restrict__ IMu,
                                             f16* __restrict__ IKu){
  __shared__ float tile[64][135];
  int blk = blockIdx.x;
  int tid = threadIdx.x;
  if (blk < BTC*102){
    int bt = blk / 102, t = blk % 102;
    int pix0 = t * 64;
    for (int r = tid; r < 64*NL; r += 256){
      int p = r / NL, nn = r % NL;
      int pix = pix0 + p;
      if (pix < PIX) tile[p][nn] = S[((size_t)bt*PIX + pix)*NL + nn];
    }
    __syncthreads();
    for (int w = tid; w < 64*NL; w += 256){
      int nn = w / 64, pp = w % 64;
      int pix = pix0 + pp;
      if (pix < PIX){
        int y = pix / WD, x = pix % WD;
        int py = y/12, ky = y%12, px = x/12, kx = x%12;
        int pa = py*9 + px, kr = ky*12 + kx;
        Su[(size_t)(bt*NL + nn)*PIX + pa*144 + kr] = (f16)tile[pp][nn];
      }
    }
  } else {
    int b2 = blk - BTC*102;            // (bt, patch)
    int bt = b2 / L45, pa = b2 % L45;
    int py = pa/9, px = pa%9;
    const float* Ib = I + (size_t)bt*EPIX;
    const float* Mb = M + (size_t)bt*PIX;
    for (int c = tid; c < CT; c += 256){
      int ch = c/144, kr = c%144;
      int ky = kr/12, kx = kr%12;
      int pix = (py*12 + ky)*WD + px*12 + kx;
      float iv = Ib[ch*PIX + pix];
      float mv = Mb[pix];
      IMu[((size_t)bt*L45 + pa)*CT + c] = (f16)(iv*mv);
      IKu[((size_t)bt*L45 + pa)*CT + c] = (f16)(iv*(1.f - mv));
    }
  }
}

// ---- kmain (round-7 verbatim EXCEPT: USE_SCR epilogue stages D in LDS, then
//      one rolled coalesced h8v copy to scr) ----
template<bool USE_SCR>
__global__ __launch_bounds__(256) void kmain(const f16* __restrict__ IMu,
                                             const f16* __restrict__ IKu,
                                             const f16* __restrict__ Su,
                                             f16* __restrict__ scr,
                                             float* __restrict__ outAcc){
  __shared__ f16 lds[(L45 + 48)*STR];           // 81,840 B -> 2 blocks/CU
  f16* bufU = lds;
  f16* bufK = lds + L45*STR;

  int b  = blockIdx.x;
  int bt = b / NL;
  int tid = threadIdx.x;

  // zero bufK rows 45..47 (K-tail contracts against zeros)
  for (int z = tid; z < 3*STR; z += 256) bufK[L45*STR + z] = (f16)0.f;

  // Phase A: bufU[p][c] = IMu[p][c]*Su[p][c%144]; bufK[p][c] = IKu[p][c]*Su[...]
  {
    const f16* IMb = IMu + (size_t)bt*L45*CT;
    const f16* IKb = IKu + (size_t)bt*L45*CT;
    const f16* Sb  = Su  + (size_t)b*PIX;
    for (int slot = tid; slot < L45*54; slot += 256){
      int p = slot / 54, cg = slot % 54;
      int c0 = cg*8;
      h8v im = *(const h8v*)&IMb[p*CT + c0];
      h8v ik = *(const h8v*)&IKb[p*CT + c0];
      h8v sv = *(const h8v*)&Sb[p*144 + (c0 % 144)];
      *(h8v*)&bufU[p*STR + c0] = im*sv;
      *(h8v*)&bufK[p*STR + c0] = ik*sv;
    }
  }
  __syncthreads();

  // ---- GEMM1: Wm(p,q) = sum_c U(p,c)*Kt(q,c).  9 16x16 tiles, 3 slots/wave.
  int wid  = tid >> 6;
  int lane = tid & 63;
  int lrow = lane & 15, lgrp = lane >> 4;

  f32x4 acc0 = {0.f,0.f,0.f,0.f}, acc1 = acc0, acc2 = acc0;
  int t0 = wid;
  int t1 = wid + 4;
  int t2 = (wid + 8 < 9) ? wid + 8 : 8;
  int ti0 = t0/3, tj0 = t0%3;
  int ti1 = t1/3, tj1 = t1%3;
  int ti2 = t2/3, tj2 = t2%3;

  const f16* uA0 = &bufU[(ti0*16 + lrow)*STR];
  const f16* uA1 = &bufU[(ti1*16 + lrow)*STR];
  const f16* uA2 = &bufU[(ti2*16 + lrow)*STR];
  const f16* kB0 = &bufK[(tj0*16 + lrow)*STR];
  const f16* kB1 = &bufK[(tj1*16 + lrow)*STR];
  const f16* kB2 = &bufK[(tj2*16 + lrow)*STR];

  for (int ks = 0; ks < 13; ++ks){
    int c0 = ks*32 + lgrp*8;
    h8v a0 = *(const h8v*)&uA0[c0];
    h8v a1 = *(const h8v*)&uA1[c0];
    h8v a2 = *(const h8v*)&uA2[c0];
    h8v b0 = *(const h8v*)&kB0[c0];
    h8v b1 = *(const h8v*)&kB1[c0];
    h8v b2 = *(const h8v*)&kB2[c0];
    acc0 = mfma_k32(a0, b0, acc0);
    acc1 = mfma_k32(a1, b1, acc1);
    acc2 = mfma_k32(a2, b2, acc2);
  }
  { // K-tail c in [416,432)
    int c0 = 416 + lgrp*4;
    h4v a0 = *(const h4v*)&uA0[c0];
    h4v a1 = *(const h4v*)&uA1[c0];
    h4v a2 = *(const h4v*)&uA2[c0];
    h4v b0 = *(const h4v*)&kB0[c0];
    h4v b1 = *(const h4v*)&kB1[c0];
    h4v b2 = *(const h4v*)&kB2[c0];
    acc0 = mfma_k16(a0, b0, acc0);
    acc1 = mfma_k16(a1, b1, acc1);
    acc2 = mfma_k16(a2, b2, acc2);
  }
  __syncthreads();

  // ---- stage raw Wm (f32) + normalized Wm (f16) over dead bufU
  float* Wm32 = (float*)lds;                       // [48][49]
  f16*   Wm16 = (f16*)((char*)lds + 48*49*4);      // [48][48]
  {
    #pragma unroll
    for (int r = 0; r < 4; ++r){
      Wm32[(ti0*16 + lgrp*4 + r)*49 + tj0*16 + lrow] = acc0[r];
      Wm32[(ti1*16 + lgrp*4 + r)*49 + tj1*16 + lrow] = acc1[r];
      Wm32[(ti2*16 + lgrp*4 + r)*49 + tj2*16 + lrow] = acc2[r];
    }
  }
  __syncthreads();

  if (tid < L45){
    float rs = 0.f;
    for (int q = 0; q < L45; ++q) rs += fabsf(Wm32[tid*49 + q]);
    float inv = 1.0f / fmaxf(rs, 1e-12f);
    for (int j = 0; j < 48; ++j)
      Wm16[tid*48 + j] = (j < L45) ? (f16)(Wm32[tid*49 + j]*inv) : (f16)0.f;
  }
  __syncthreads();

  // ---- GEMM2: D(i,c) = sum_j Wm(i,j)*Kt(j,c). 3 i-tiles x 27 c-tiles.
  h8v aw0 = *(const h8v*)&Wm16[( 0 + lrow)*48 + lgrp*8];
  h8v aw1 = *(const h8v*)&Wm16[(16 + lrow)*48 + lgrp*8];
  h8v aw2 = *(const h8v*)&Wm16[(32 + lrow)*48 + lgrp*8];
  h4v at0 = *(const h4v*)&Wm16[( 0 + lrow)*48 + 32 + lgrp*4];
  h4v at1 = *(const h4v*)&Wm16[(16 + lrow)*48 + 32 + lgrp*4];
  h4v at2 = *(const h4v*)&Wm16[(32 + lrow)*48 + 32 + lgrp*4];

  if (USE_SCR) __syncthreads();   // frags now in regs; Dl may clobber Wm region

  f16* Dl = lds;                  // D[i][c] at lds[i*432+c], max 19439 < bufK@19800

  for (int cb = wid; cb < 27; cb += 4){
    int cbase = cb*16 + lrow;
    h8v bK; h4v bT;
    #pragma unroll
    for (int r = 0; r < 8; ++r) bK[r] = bufK[(lgrp*8 + r)*STR + cbase];
    #pragma unroll
    for (int r = 0; r < 4; ++r) bT[r] = bufK[(32 + lgrp*4 + r)*STR + cbase];

    int ch  = cb / 9;
    int kr  = (cb % 9)*16 + lrow;
    int ky  = kr / 12, kx = kr - ky*12;
    int pixc = ch*PIX + ky*WD + kx;

    f32x4 d0 = {0.f,0.f,0.f,0.f}, d1 = d0, d2 = d0;
    d0 = mfma_k32(aw0, bK, d0);  d0 = mfma_k16(at0, bT, d0);
    d1 = mfma_k32(aw1, bK, d1);  d1 = mfma_k16(at1, bT, d1);
    d2 = mfma_k32(aw2, bK, d2);  d2 = mfma_k16(at2, bT, d2);

    #pragma unroll
    for (int r = 0; r < 4; ++r){
      { int i = 0 + lgrp*4 + r;
        if (USE_SCR) Dl[i*CT + cbase] = (f16)d0[r];
        else {
          int iy = i/9, ix = i - iy*9;
          atomicAdd(&outAcc[(size_t)bt*EPIX + pixc + (iy*12)*WD + ix*12], (float)d0[r]); } }
      { int i = 16 + lgrp*4 + r;
        if (USE_SCR) Dl[i*CT + cbase] = (f16)d1[r];
        else {
          int iy = i/9, ix = i - iy*9;
          atomicAdd(&outAcc[(size_t)bt*EPIX + pixc + (iy*12)*WD + ix*12], (float)d1[r]); } }
      { int i = 32 + lgrp*4 + r;
        if (i < L45){
          if (USE_SCR) Dl[i*CT + cbase] = (f16)d2[r];
          else {
            int iy = i/9, ix = i - iy*9;
            atomicAdd(&outAcc[(size_t)bt*EPIX + pixc + (iy*12)*WD + ix*12], (float)d2[r]); } } }
    }
  }

  if (USE_SCR){
    __syncthreads();             // all D staged
    f16* sb = scr + (size_t)b*L45*CT;
    for (int slot = tid; slot < L45*54; slot += 256){
      h8v v = *(const h8v*)&Dl[slot*8];
      *(h8v*)&sb[slot*8] = v;    // fully coalesced 16B stores
    }
  }
}

// ---- kreduce (round-7 verbatim): sum over 133 layers in [b][pa][c], blend, scatter
__global__ __launch_bounds__(256) void kreduce(const float* __restrict__ I,
                                               const float* __restrict__ M,
                                               const f16* __restrict__ scr,
                                               float* __restrict__ out){
  int t = blockIdx.x*256 + threadIdx.x;
  int sub = t & 7, g = t >> 3;
  if (g >= BTC*L45*108) return;
  int bt = g / (L45*108), rem = g % (L45*108);
  int pa = rem / 108, c4 = rem % 108;
  int c0 = c4*4;
  const f16* p = scr + ((size_t)(bt*NL)*L45 + pa)*CT + c0;
  f32x4 a = {0.f,0.f,0.f,0.f};
  #pragma unroll
  for (int k = 0; k < 17; ++k){
    int nn = sub + k*8;
    int nc = nn < NL ? nn : NL-1;
    h4v v = *(const h4v*)&p[(size_t)nc*L45*CT];
    if (nn < NL){
      a[0] += (float)v[0]; a[1] += (float)v[1];
      a[2] += (float)v[2]; a[3] += (float)v[3];
    }
  }
  #pragma unroll
  for (int s = 1; s < 8; s <<= 1){
    a[0] += __shfl_xor(a[0], s); a[1] += __shfl_xor(a[1], s);
    a[2] += __shfl_xor(a[2], s); a[3] += __shfl_xor(a[3], s);
  }
  if (sub == 0){
    int ch = c0/144, kr = c0%144, ky = kr/12, kx = kr%12;
    int py = pa/9, px = pa%9;
    int pix = (py*12 + ky)*WD + px*12 + kx;
    size_t io = (size_t)bt*EPIX + ch*PIX + pix;
    float4 iv = *(const float4*)&I[io];
    float4 mv = *(const float4*)&M[(size_t)bt*PIX + pix];
    float4 o;
    o.x = iv.x*(1.f-mv.x) + a[0]*mv.x;
    o.y = iv.y*(1.f-mv.y) + a[1]*mv.y;
    o.z = iv.z*(1.f-mv.z) + a[2]*mv.z;
    o.w = iv.w*(1.f-mv.w) + a[3]*mv.w;
    *(float4*)&out[io] = o;
  }
}

__global__ __launch_bounds__(256) void kfinal(const float* __restrict__ I,
                                              const float* __restrict__ M,
                                              float* __restrict__ out){
  int g = blockIdx.x*256 + threadIdx.x;
  if (g >= BTC*EPIX) return;
  int bt = g / EPIX, e = g % EPIX;
  float a = out[g];
  float m = M[bt*PIX + (e % PIX)];
  out[g] = I[g]*(1.f - m) + a*m;
}

extern "C" void kernel_launch(void* const* d_in, const int* in_sizes, int n_in,
                              void* d_out, int out_size, void* d_ws, size_t ws_size,
                              hipStream_t stream){
  const float* I = (const float*)d_in[0];
  const float* S = (const float*)d_in[1];
  const float* M = (const float*)d_in[2];
  float* out = (float*)d_out;

  const size_t needSu  = (size_t)NB*PIX*sizeof(f16);      //  6,894,720
  const size_t needIM  = (size_t)BTC*L45*CT*sizeof(f16);  //    155,520 each
  const size_t needScr = (size_t)NB*L45*CT*sizeof(f16);   // 20,684,160
  const size_t prepSz  = needSu + 2*needIM;

  f16* Su  = (f16*)d_ws;
  f16* IMu = (f16*)((char*)d_ws + needSu);
  f16* IKu = (f16*)((char*)d_ws + needSu + needIM);
  f16* scr = (f16*)((char*)d_ws + prepSz);
  bool useScr = ws_size >= prepSz + needScr;

  kprep<<<BTC*102 + BTC*L45, 256, 0, stream>>>(S, I, M, Su, IMu, IKu);

  if (useScr){
    kmain<true ><<<NB, 256, 0, stream>>>(IMu, IKu, Su, scr, out);
    kreduce<<<((BTC*L45*108)*8 + 255)/256, 256, 0, stream>>>(I, M, scr, out);
  } else {
    (void)hipMemsetAsync(out, 0, (size_t)BTC*EPIX*sizeof(float), stream);
    kmain<false><<<NB, 256, 0, stream>>>(IMu, IKu, Su, scr, out);
    kfinal<<<(BTC*EPIX + 255)/256, 256, 0, stream>>>(I, M, out);
  }
}

// Round 10
// 103.010 us; speedup vs baseline: 1.3712x; 1.0779x over previous
//
#include <hip/hip_runtime.h>

#define NL 133
#define HT 60
#define WD 108
#define PIX (HT*WD)          // 6480
#define CT 432               // 3*12*12 channels after unfold
#define L45 45               // patches
#define STR 440              // LDS row stride in halves (880B)
#define BTC 4
#define NB (BTC*NL)          // 532
#define EPIX (3*PIX)         // 19440

typedef _Float16 f16;
typedef _Float16 h4v __attribute__((ext_vector_type(4)));
typedef _Float16 h8v __attribute__((ext_vector_type(8)));
typedef float f32x4 __attribute__((ext_vector_type(4)));

__device__ __forceinline__ f32x4 mfma_k32(h8v a, h8v b, f32x4 c){
  return __builtin_amdgcn_mfma_f32_16x16x32_f16(a, b, c, 0, 0, 0);
}
__device__ __forceinline__ f32x4 mfma_k16(h4v a, h4v b, f32x4 c){
  return __builtin_amdgcn_mfma_f32_16x16x16f16(a, b, c, 0, 0, 0);
}

// ---- kprep: blocks [0,408): S transpose+unfold -> Su[b][pa*144+kr]
//      blocks [408,588): IMu/IKu[bt][pa][c] = unfold(I*M), unfold(I*(1-M)) f16
__global__ __launch_bounds__(256) void kprep(const float* __restrict__ S,
                                             const float* __restrict__ I,
                                             const float* __restrict__ M,
                                             f16* __restrict__ Su,
                                             f16* __restrict__ IMu,
                                             f16* __restrict__ IKu){
  __shared__ float tile[64][135];
  int blk = blockIdx.x;
  int tid = threadIdx.x;
  if (blk < BTC*102){
    int bt = blk / 102, t = blk % 102;
    int pix0 = t * 64;
    // Load side: the 64-pixel chunk is 64*133 = 8512 CONTIGUOUS floats,
    // 16B-aligned (64*133*4 = 34048 = 16*2128). Load as 2128 float4.
    int npx = PIX - pix0; if (npx > 64) npx = 64;
    int nval = npx * NL;                       // whole float4s (nval % 4 == 0 here)
    const float* Sflat = &S[((size_t)bt*PIX + pix0)*NL];
    for (int f4 = tid; f4 < 2128; f4 += 256){
      int f = f4*4;
      if (f < nval){
        float4 v = *(const float4*)&Sflat[f];
        int p0 = (f  ) / NL, n0 = (f  ) - p0*NL;
        int p1 = (f+1) / NL, n1 = (f+1) - p1*NL;
        int p2 = (f+2) / NL, n2 = (f+2) - p2*NL;
        int p3 = (f+3) / NL, n3 = (f+3) - p3*NL;
        tile[p0][n0] = v.x;
        tile[p1][n1] = v.y;
        tile[p2][n2] = v.z;
        tile[p3][n3] = v.w;
      }
    }
    __syncthreads();
    for (int w = tid; w < 64*NL; w += 256){
      int nn = w / 64, pp = w % 64;
      int pix = pix0 + pp;
      if (pix < PIX){
        int y = pix / WD, x = pix % WD;
        int py = y/12, ky = y%12, px = x/12, kx = x%12;
        int pa = py*9 + px, kr = ky*12 + kx;
        Su[(size_t)(bt*NL + nn)*PIX + pa*144 + kr] = (f16)tile[pp][nn];
      }
    }
  } else {
    int b2 = blk - BTC*102;            // (bt, patch)
    int bt = b2 / L45, pa = b2 % L45;
    int py = pa/9, px = pa%9;
    const float* Ib = I + (size_t)bt*EPIX;
    const float* Mb = M + (size_t)bt*PIX;
    for (int c = tid; c < CT; c += 256){
      int ch = c/144, kr = c%144;
      int ky = kr/12, kx = kr%12;
      int pix = (py*12 + ky)*WD + px*12 + kx;
      float iv = Ib[ch*PIX + pix];
      float mv = Mb[pix];
      IMu[((size_t)bt*L45 + pa)*CT + c] = (f16)(iv*mv);
      IKu[((size_t)bt*L45 + pa)*CT + c] = (f16)(iv*(1.f - mv));
    }
  }
}

// ---- kmain (round-9 verbatim EXCEPT: parallel 4-thread/row L1 normalize) ----
template<bool USE_SCR>
__global__ __launch_bounds__(256) void kmain(const f16* __restrict__ IMu,
                                             const f16* __restrict__ IKu,
                                             const f16* __restrict__ Su,
                                             f16* __restrict__ scr,
                                             float* __restrict__ outAcc){
  __shared__ f16 lds[(L45 + 48)*STR];           // 81,840 B -> 2 blocks/CU
  f16* bufU = lds;
  f16* bufK = lds + L45*STR;

  int b  = blockIdx.x;
  int bt = b / NL;
  int tid = threadIdx.x;

  // zero bufK rows 45..47 (K-tail contracts against zeros)
  for (int z = tid; z < 3*STR; z += 256) bufK[L45*STR + z] = (f16)0.f;

  // Phase A: bufU[p][c] = IMu[p][c]*Su[p][c%144]; bufK[p][c] = IKu[p][c]*Su[...]
  {
    const f16* IMb = IMu + (size_t)bt*L45*CT;
    const f16* IKb = IKu + (size_t)bt*L45*CT;
    const f16* Sb  = Su  + (size_t)b*PIX;
    for (int slot = tid; slot < L45*54; slot += 256){
      int p = slot / 54, cg = slot % 54;
      int c0 = cg*8;
      h8v im = *(const h8v*)&IMb[p*CT + c0];
      h8v ik = *(const h8v*)&IKb[p*CT + c0];
      h8v sv = *(const h8v*)&Sb[p*144 + (c0 % 144)];
      *(h8v*)&bufU[p*STR + c0] = im*sv;
      *(h8v*)&bufK[p*STR + c0] = ik*sv;
    }
  }
  __syncthreads();

  // ---- GEMM1: Wm(p,q) = sum_c U(p,c)*Kt(q,c).  9 16x16 tiles, 3 slots/wave.
  int wid  = tid >> 6;
  int lane = tid & 63;
  int lrow = lane & 15, lgrp = lane >> 4;

  f32x4 acc0 = {0.f,0.f,0.f,0.f}, acc1 = acc0, acc2 = acc0;
  int t0 = wid;
  int t1 = wid + 4;
  int t2 = (wid + 8 < 9) ? wid + 8 : 8;
  int ti0 = t0/3, tj0 = t0%3;
  int ti1 = t1/3, tj1 = t1%3;
  int ti2 = t2/3, tj2 = t2%3;

  const f16* uA0 = &bufU[(ti0*16 + lrow)*STR];
  const f16* uA1 = &bufU[(ti1*16 + lrow)*STR];
  const f16* uA2 = &bufU[(ti2*16 + lrow)*STR];
  const f16* kB0 = &bufK[(tj0*16 + lrow)*STR];
  const f16* kB1 = &bufK[(tj1*16 + lrow)*STR];
  const f16* kB2 = &bufK[(tj2*16 + lrow)*STR];

  for (int ks = 0; ks < 13; ++ks){
    int c0 = ks*32 + lgrp*8;
    h8v a0 = *(const h8v*)&uA0[c0];
    h8v a1 = *(const h8v*)&uA1[c0];
    h8v a2 = *(const h8v*)&uA2[c0];
    h8v b0 = *(const h8v*)&kB0[c0];
    h8v b1 = *(const h8v*)&kB1[c0];
    h8v b2 = *(const h8v*)&kB2[c0];
    acc0 = mfma_k32(a0, b0, acc0);
    acc1 = mfma_k32(a1, b1, acc1);
    acc2 = mfma_k32(a2, b2, acc2);
  }
  { // K-tail c in [416,432)
    int c0 = 416 + lgrp*4;
    h4v a0 = *(const h4v*)&uA0[c0];
    h4v a1 = *(const h4v*)&uA1[c0];
    h4v a2 = *(const h4v*)&uA2[c0];
    h4v b0 = *(const h4v*)&kB0[c0];
    h4v b1 = *(const h4v*)&kB1[c0];
    h4v b2 = *(const h4v*)&kB2[c0];
    acc0 = mfma_k16(a0, b0, acc0);
    acc1 = mfma_k16(a1, b1, acc1);
    acc2 = mfma_k16(a2, b2, acc2);
  }
  __syncthreads();

  // ---- stage raw Wm (f32) + normalized Wm (f16) over dead bufU
  float* Wm32 = (float*)lds;                       // [48][49]
  f16*   Wm16 = (f16*)((char*)lds + 48*49*4);      // [48][48]
  {
    #pragma unroll
    for (int r = 0; r < 4; ++r){
      Wm32[(ti0*16 + lgrp*4 + r)*49 + tj0*16 + lrow] = acc0[r];
      Wm32[(ti1*16 + lgrp*4 + r)*49 + tj1*16 + lrow] = acc1[r];
      Wm32[(ti2*16 + lgrp*4 + r)*49 + tj2*16 + lrow] = acc2[r];
    }
  }
  __syncthreads();

  // ---- L1 normalize: 4 threads per row (rows 0..44). Cols 45..47 of Wm32 are
  //      exact zeros, so including them in the abs-sum is identity.
  {
    int row = tid >> 2, part = tid & 3;
    if (row < L45){
      int j0 = part*12;
      float rs = 0.f;
      for (int q = j0; q < j0+12; ++q) rs += fabsf(Wm32[row*49 + q]);
      rs += __shfl_xor(rs, 1);
      rs += __shfl_xor(rs, 2);
      float inv = 1.0f / fmaxf(rs, 1e-12f);
      for (int j = j0; j < j0+12; ++j)
        Wm16[row*48 + j] = (j < L45) ? (f16)(Wm32[row*49 + j]*inv) : (f16)0.f;
    }
  }
  __syncthreads();

  // ---- GEMM2: D(i,c) = sum_j Wm(i,j)*Kt(j,c). 3 i-tiles x 27 c-tiles.
  h8v aw0 = *(const h8v*)&Wm16[( 0 + lrow)*48 + lgrp*8];
  h8v aw1 = *(const h8v*)&Wm16[(16 + lrow)*48 + lgrp*8];
  h8v aw2 = *(const h8v*)&Wm16[(32 + lrow)*48 + lgrp*8];
  h4v at0 = *(const h4v*)&Wm16[( 0 + lrow)*48 + 32 + lgrp*4];
  h4v at1 = *(const h4v*)&Wm16[(16 + lrow)*48 + 32 + lgrp*4];
  h4v at2 = *(const h4v*)&Wm16[(32 + lrow)*48 + 32 + lgrp*4];

  if (USE_SCR) __syncthreads();   // frags now in regs; Dl may clobber Wm region

  f16* Dl = lds;                  // D[i][c] at lds[i*432+c], max 19439 < bufK@19800

  for (int cb = wid; cb < 27; cb += 4){
    int cbase = cb*16 + lrow;
    h8v bK; h4v bT;
    #pragma unroll
    for (int r = 0; r < 8; ++r) bK[r] = bufK[(lgrp*8 + r)*STR + cbase];
    #pragma unroll
    for (int r = 0; r < 4; ++r) bT[r] = bufK[(32 + lgrp*4 + r)*STR + cbase];

    int ch  = cb / 9;
    int kr  = (cb % 9)*16 + lrow;
    int ky  = kr / 12, kx = kr - ky*12;
    int pixc = ch*PIX + ky*WD + kx;

    f32x4 d0 = {0.f,0.f,0.f,0.f}, d1 = d0, d2 = d0;
    d0 = mfma_k32(aw0, bK, d0);  d0 = mfma_k16(at0, bT, d0);
    d1 = mfma_k32(aw1, bK, d1);  d1 = mfma_k16(at1, bT, d1);
    d2 = mfma_k32(aw2, bK, d2);  d2 = mfma_k16(at2, bT, d2);

    #pragma unroll
    for (int r = 0; r < 4; ++r){
      { int i = 0 + lgrp*4 + r;
        if (USE_SCR) Dl[i*CT + cbase] = (f16)d0[r];
        else {
          int iy = i/9, ix = i - iy*9;
          atomicAdd(&outAcc[(size_t)bt*EPIX + pixc + (iy*12)*WD + ix*12], (float)d0[r]); } }
      { int i = 16 + lgrp*4 + r;
        if (USE_SCR) Dl[i*CT + cbase] = (f16)d1[r];
        else {
          int iy = i/9, ix = i - iy*9;
          atomicAdd(&outAcc[(size_t)bt*EPIX + pixc + (iy*12)*WD + ix*12], (float)d1[r]); } }
      { int i = 32 + lgrp*4 + r;
        if (i < L45){
          if (USE_SCR) Dl[i*CT + cbase] = (f16)d2[r];
          else {
            int iy = i/9, ix = i - iy*9;
            atomicAdd(&outAcc[(size_t)bt*EPIX + pixc + (iy*12)*WD + ix*12], (float)d2[r]); } } }
    }
  }

  if (USE_SCR){
    __syncthreads();             // all D staged
    f16* sb = scr + (size_t)b*L45*CT;
    for (int slot = tid; slot < L45*54; slot += 256){
      h8v v = *(const h8v*)&Dl[slot*8];
      *(h8v*)&sb[slot*8] = v;    // fully coalesced 16B stores
    }
  }
}

// ---- kreduce (round-9 verbatim): sum over 133 layers in [b][pa][c], blend, scatter
__global__ __launch_bounds__(256) void kreduce(const float* __restrict__ I,
                                               const float* __restrict__ M,
                                               const f16* __restrict__ scr,
                                               float* __restrict__ out){
  int t = blockIdx.x*256 + threadIdx.x;
  int sub = t & 7, g = t >> 3;
  if (g >= BTC*L45*108) return;
  int bt = g / (L45*108), rem = g % (L45*108);
  int pa = rem / 108, c4 = rem % 108;
  int c0 = c4*4;
  const f16* p = scr + ((size_t)(bt*NL)*L45 + pa)*CT + c0;
  f32x4 a = {0.f,0.f,0.f,0.f};
  #pragma unroll
  for (int k = 0; k < 17; ++k){
    int nn = sub + k*8;
    int nc = nn < NL ? nn : NL-1;
    h4v v = *(const h4v*)&p[(size_t)nc*L45*CT];
    if (nn < NL){
      a[0] += (float)v[0]; a[1] += (float)v[1];
      a[2] += (float)v[2]; a[3] += (float)v[3];
    }
  }
  #pragma unroll
  for (int s = 1; s < 8; s <<= 1){
    a[0] += __shfl_xor(a[0], s); a[1] += __shfl_xor(a[1], s);
    a[2] += __shfl_xor(a[2], s); a[3] += __shfl_xor(a[3], s);
  }
  if (sub == 0){
    int ch = c0/144, kr = c0%144, ky = kr/12, kx = kr%12;
    int py = pa/9, px = pa%9;
    int pix = (py*12 + ky)*WD + px*12 + kx;
    size_t io = (size_t)bt*EPIX + ch*PIX + pix;
    float4 iv = *(const float4*)&I[io];
    float4 mv = *(const float4*)&M[(size_t)bt*PIX + pix];
    float4 o;
    o.x = iv.x*(1.f-mv.x) + a[0]*mv.x;
    o.y = iv.y*(1.f-mv.y) + a[1]*mv.y;
    o.z = iv.z*(1.f-mv.z) + a[2]*mv.z;
    o.w = iv.w*(1.f-mv.w) + a[3]*mv.w;
    *(float4*)&out[io] = o;
  }
}

__global__ __launch_bounds__(256) void kfinal(const float* __restrict__ I,
                                              const float* __restrict__ M,
                                              float* __restrict__ out){
  int g = blockIdx.x*256 + threadIdx.x;
  if (g >= BTC*EPIX) return;
  int bt = g / EPIX, e = g % EPIX;
  float a = out[g];
  float m = M[bt*PIX + (e % PIX)];
  out[g] = I[g]*(1.f - m) + a*m;
}

extern "C" void kernel_launch(void* const* d_in, const int* in_sizes, int n_in,
                              void* d_out, int out_size, void* d_ws, size_t ws_size,
                              hipStream_t stream){
  const float* I = (const float*)d_in[0];
  const float* S = (const float*)d_in[1];
  const float* M = (const float*)d_in[2];
  float* out = (float*)d_out;

  const size_t needSu  = (size_t)NB*PIX*sizeof(f16);      //  6,894,720
  const size_t needIM  = (size_t)BTC*L45*CT*sizeof(f16);  //    155,520 each
  const size_t needScr = (size_t)NB*L45*CT*sizeof(f16);   // 20,684,160
  const size_t prepSz  = needSu + 2*needIM;

  f16* Su  = (f16*)d_ws;
  f16* IMu = (f16*)((char*)d_ws + needSu);
  f16* IKu = (f16*)((char*)d_ws + needSu + needIM);
  f16* scr = (f16*)((char*)d_ws + prepSz);
  bool useScr = ws_size >= prepSz + needScr;

  kprep<<<BTC*102 + BTC*L45, 256, 0, stream>>>(S, I, M, Su, IMu, IKu);

  if (useScr){
    kmain<true ><<<NB, 256, 0, stream>>>(IMu, IKu, Su, scr, out);
    kreduce<<<((BTC*L45*108)*8 + 255)/256, 256, 0, stream>>>(I, M, scr, out);
  } else {
    (void)hipMemsetAsync(out, 0, (size_t)BTC*EPIX*sizeof(float), stream);
    kmain<false><<<NB, 256, 0, stream>>>(IMu, IKu, Su, scr, out);
    kfinal<<<(BTC*EPIX + 255)/256, 256, 0, stream>>>(I, M, out);
  }
}